// Round 1
// baseline (74.305 us; speedup 1.0000x reference)
//
#include <hip/hip_runtime.h>
#include <math.h>

#define DT 0.005f
#define NBLOCKS 2048
#define NTHREADS 256

__global__ __launch_bounds__(NTHREADS) void pos_loss_partial(
    const float* __restrict__ quat,     // B*4
    const float* __restrict__ tpos,     // B*3
    const float* __restrict__ bias,     // B*3
    const float* __restrict__ batchX,   // B*S*F
    const float* __restrict__ pos_all,  // N*3
    const float* __restrict__ vel_all,  // N*3
    const float* __restrict__ grav,     // 3
    const int*   __restrict__ indices,  // B
    const int*   __restrict__ seq_len_p,// 1
    int B, int SF,
    float* __restrict__ partials)       // NBLOCKS
{
    const int S = *seq_len_p;
    const int F = SF / S;
    const int last_off = (S - 1) * F;
    const float gx = grav[0], gy = grav[1], gz = grav[2];
    const float half_dt2 = 0.5f * DT * DT;

    float hsum = 0.f;

    for (int i = blockIdx.x * blockDim.x + threadIdx.x; i < B;
         i += gridDim.x * blockDim.x) {

        // quaternion (coalesced float4)
        float4 q = reinterpret_cast<const float4*>(quat)[i];

        // true position
        const float* tp = tpos + (size_t)i * 3;
        float tpx = tp[0], tpy = tp[1], tpz = tp[2];

        // bias
        const float* bp = bias + (size_t)i * 3;
        float bx = bp[0], by = bp[1], bz = bp[2];

        // last accel sample from batch_X
        const float* xb = batchX + (size_t)i * SF + last_off;
        float ax = xb[0] - bx;
        float ay = xb[1] - by;
        float az = xb[2] - bz;

        // gather p0 / v0
        int idx = indices[i] - (S - 1);
        if (idx < 0) idx = 0;
        const float* pp = pos_all + (size_t)idx * 3;
        const float* vp = vel_all + (size_t)idx * 3;
        float p0x = pp[0], p0y = pp[1], p0z = pp[2];
        float v0x = vp[0], v0y = vp[1], v0z = vp[2];

        // quat_rotate(q, a): t = q * (0, a)
        float t0 = -(q.y * ax + q.z * ay + q.w * az);
        float t1 =   q.x * ax + q.z * az - q.w * ay;
        float t2 =   q.x * ay - q.y * az + q.w * ax;
        float t3 =   q.x * az + q.y * ay - q.z * ax;
        // (t * q_conj) vector part
        float rx = -t0 * q.y + t1 * q.x - t2 * q.w + t3 * q.z;
        float ry = -t0 * q.z + t1 * q.w + t2 * q.x - t3 * q.y;
        float rz = -t0 * q.w - t1 * q.z + t2 * q.y + t3 * q.x;

        // pred = p0 + v0*DT + 0.5*g*DT^2 + 0.5*rot*DT^2
        float px = p0x + v0x * DT + half_dt2 * gx + half_dt2 * rx;
        float py = p0y + v0y * DT + half_dt2 * gy + half_dt2 * ry;
        float pz = p0z + v0z * DT + half_dt2 * gz + half_dt2 * rz;

        float dx = px - tpx, dy = py - tpy, dz = pz - tpz;

        float adx = fabsf(dx), ady = fabsf(dy), adz = fabsf(dz);
        hsum += (adx < 1.f) ? 0.5f * dx * dx : adx - 0.5f;
        hsum += (ady < 1.f) ? 0.5f * dy * dy : ady - 0.5f;
        hsum += (adz < 1.f) ? 0.5f * dz * dz : adz - 0.5f;
    }

    // wave-64 reduce
    for (int off = 32; off > 0; off >>= 1)
        hsum += __shfl_down(hsum, off);

    __shared__ float wsum[NTHREADS / 64];
    int lane = threadIdx.x & 63;
    int wid  = threadIdx.x >> 6;
    if (lane == 0) wsum[wid] = hsum;
    __syncthreads();

    if (threadIdx.x == 0) {
        float s = 0.f;
        for (int w = 0; w < NTHREADS / 64; ++w) s += wsum[w];
        partials[blockIdx.x] = s;
    }
}

__global__ __launch_bounds__(NTHREADS) void pos_loss_finish(
    const float* __restrict__ partials, int nb, float inv_cnt,
    float* __restrict__ out)
{
    float s = 0.f;
    for (int i = threadIdx.x; i < nb; i += NTHREADS) s += partials[i];

    for (int off = 32; off > 0; off >>= 1)
        s += __shfl_down(s, off);

    __shared__ float wsum[NTHREADS / 64];
    int lane = threadIdx.x & 63;
    int wid  = threadIdx.x >> 6;
    if (lane == 0) wsum[wid] = s;
    __syncthreads();

    if (threadIdx.x == 0) {
        float tot = 0.f;
        for (int w = 0; w < NTHREADS / 64; ++w) tot += wsum[w];
        out[0] = tot * inv_cnt;
    }
}

extern "C" void kernel_launch(void* const* d_in, const int* in_sizes, int n_in,
                              void* d_out, int out_size, void* d_ws, size_t ws_size,
                              hipStream_t stream) {
    const float* quat    = (const float*)d_in[0];
    const float* tpos    = (const float*)d_in[1];
    const float* bias    = (const float*)d_in[2];
    const float* batchX  = (const float*)d_in[3];
    const float* pos_all = (const float*)d_in[4];
    const float* vel_all = (const float*)d_in[5];
    const float* grav    = (const float*)d_in[6];
    const int*   indices = (const int*)d_in[7];
    const int*   seqlen  = (const int*)d_in[8];

    const int B  = in_sizes[0] / 4;
    const int SF = in_sizes[3] / B;

    float* partials = (float*)d_ws;
    float inv_cnt = (float)(1.0 / (3.0 * (double)B));

    pos_loss_partial<<<NBLOCKS, NTHREADS, 0, stream>>>(
        quat, tpos, bias, batchX, pos_all, vel_all, grav, indices, seqlen,
        B, SF, partials);

    pos_loss_finish<<<1, NTHREADS, 0, stream>>>(
        partials, NBLOCKS, inv_cnt, (float*)d_out);
}